// Round 1
// baseline (30994.229 us; speedup 1.0000x reference)
//
#include <hip/hip_runtime.h>

// Problem dims
#define Bn   64
#define Sn   512
#define Dn   768
#define Hn   384
#define G4n  1536   // 4*H
#define Tn   9
#define SCHn 128    // S-chunk for gates staging
#define NCH  4      // Sn / SCHn

// ---- workspace layout (in floats) ----
// WihT  [2][2][768][1536]
// WhhT  [2][2][384][1536]
// gates [2][64][128][1536]   (one S-chunk, both dirs)
// h1    [64][512][768]       (layer-1 output = layer-2 input)
// emP   [2][64][512][9]      (layer-2 per-direction emission partials)
// em    [64][512][9]
// hstate[2][64][384], cstate[2][64][384]
// lossp [64]
#define OFF_WIHT  0ull
#define SZ_WIHT   (4ull * Dn * G4n)
#define OFF_WHHT  (OFF_WIHT + SZ_WIHT)
#define SZ_WHHT   (4ull * Hn * G4n)
#define OFF_GATES (OFF_WHHT + SZ_WHHT)
#define SZ_GATES  (2ull * Bn * SCHn * G4n)
#define OFF_H1    (OFF_GATES + SZ_GATES)
#define SZ_H1     ((unsigned long long)Bn * Sn * Dn)
#define OFF_EMP   (OFF_H1 + SZ_H1)
#define SZ_EMP    (2ull * Bn * Sn * Tn)
#define OFF_EM    (OFF_EMP + SZ_EMP)
#define SZ_EM     ((unsigned long long)Bn * Sn * Tn)
#define OFF_HST   (OFF_EM + SZ_EM)
#define SZ_HST    (2ull * Bn * Hn)
#define OFF_CST   (OFF_HST + SZ_HST)
#define SZ_CST    (2ull * Bn * Hn)
#define OFF_LP    (OFF_CST + SZ_CST)

static __device__ __forceinline__ float sigf(float x) { return 1.f / (1.f + expf(-x)); }

// ---------------- weight transpose: [ld][N=1536][K] -> [ld][K][N] ----------------
__global__ void transpose_w(const float* __restrict__ in, float* __restrict__ out,
                            int K, int total)
{
    const int nk = G4n * K;
    for (int idx = blockIdx.x * blockDim.x + threadIdx.x; idx < total;
         idx += gridDim.x * blockDim.x) {
        const int ld = idx / nk;
        const int r  = idx - ld * nk;
        const int k  = r / G4n;
        const int n  = r - k * G4n;
        out[idx] = in[(size_t)ld * nk + (size_t)n * K + k];
    }
}

// ---------------- gates GEMM: G[m][n] = A_row(m) . WihT[:,n] + bias[n] ----------------
// m = (dir*64 + b)*128 + j ; row of A is input[b][s(dir,chunk,j)][:]
// grid: (12, 128), block 256, BM=BN=128, BK=8, 8x8 per thread
__global__ __launch_bounds__(256) void gemm_gates(
    const float* __restrict__ A,      // [64][512][768] (bert or h1)
    const float* __restrict__ WihT,   // [2][2][768][1536]
    const float* __restrict__ bvec,   // [2][2][1536]
    float* __restrict__ G,            // [2][64][128][1536]
    int layer, int chunk)
{
    const int tid = threadIdx.x;
    const int nb  = blockIdx.x;       // 0..11
    const int mb  = blockIdx.y;       // 0..127
    const int m0  = mb * 128;
    const int dir = mb >> 6;
    const int n0c = nb * 128;

    __shared__ __align__(16) float As[8][128];
    __shared__ __align__(16) float Bs[8][128];

    const float* BT   = WihT + (size_t)(layer * 2 + dir) * Dn * G4n;
    const float* bias = bvec + (size_t)(layer * 2 + dir) * G4n;

    // A-tile load mapping (fixed per thread)
    const int lrow = tid >> 1;            // 0..127
    const int kq   = (tid & 1) * 4;
    {
    }
    const int grow = m0 + lrow;
    const int rem  = grow & 8191;
    const int bb   = rem >> 7;
    const int j    = rem & 127;
    const int p    = chunk * SCHn + j;
    const int s    = dir ? (Sn - 1 - p) : p;
    const float* arow = A + ((size_t)bb * Sn + s) * Dn;

    // B-tile load mapping
    const int kr = tid >> 5;              // 0..7
    const int nq = (tid & 31) * 4;

    const int tx = tid & 15, ty = tid >> 4;

    float acc[8][8];
    #pragma unroll
    for (int i = 0; i < 8; ++i)
        #pragma unroll
        for (int q = 0; q < 8; ++q) acc[i][q] = 0.f;

    for (int k0 = 0; k0 < Dn; k0 += 8) {
        const float4 av = *(const float4*)(arow + k0 + kq);
        const float4 bv = *(const float4*)(BT + (size_t)(k0 + kr) * G4n + n0c + nq);
        __syncthreads();
        As[kq + 0][lrow] = av.x;
        As[kq + 1][lrow] = av.y;
        As[kq + 2][lrow] = av.z;
        As[kq + 3][lrow] = av.w;
        *(float4*)&Bs[kr][nq] = bv;
        __syncthreads();
        #pragma unroll
        for (int kk = 0; kk < 8; ++kk) {
            float a8[8], b8[8];
            #pragma unroll
            for (int i = 0; i < 8; ++i) a8[i] = As[kk][ty * 8 + i];
            #pragma unroll
            for (int i = 0; i < 8; ++i) b8[i] = Bs[kk][tx * 8 + i];
            #pragma unroll
            for (int i = 0; i < 8; ++i)
                #pragma unroll
                for (int q = 0; q < 8; ++q) acc[i][q] += a8[i] * b8[q];
        }
    }

    float bias8[8];
    #pragma unroll
    for (int q = 0; q < 8; ++q) bias8[q] = bias[n0c + tx * 8 + q];

    #pragma unroll
    for (int i = 0; i < 8; ++i) {
        const int row = m0 + ty * 8 + i;
        float* gr = G + (size_t)row * G4n + n0c + tx * 8;
        #pragma unroll
        for (int q = 0; q < 8; ++q) gr[q] = acc[i][q] + bias8[q];
    }
}

// ---------------- LSTM recurrence over one S-chunk ----------------
// 128 workgroups = (dir, b); XCD-aware: bid&7 in 0..3 -> fwd, 4..7 -> bwd
__global__ __launch_bounds__(256) void lstm_chunk(
    const float* __restrict__ gates,   // [2][64][128][1536]
    const float* __restrict__ WhhT,    // [2][2][384][1536]
    const float* __restrict__ fcw,     // [9][768]
    float* __restrict__ h1,            // [64][512][768]  (layer 0 writes)
    float* __restrict__ emP,           // [2][64][512][9] (layer 1 writes)
    float* __restrict__ hstate, float* __restrict__ cstate,
    int layer, int chunk)
{
    const int tid = threadIdx.x;
    const int bid = blockIdx.x;
    const int xcd = bid & 7;
    const int dir = (xcd >= 4) ? 1 : 0;
    const int b   = ((bid >> 3) << 2) + (xcd & 3);

    __shared__ __align__(16) float hs[Hn];
    __shared__ __align__(16) float cs[Hn];
    __shared__ __align__(16) float gbuf[G4n];

    float* hst = hstate + ((size_t)dir * Bn + b) * Hn;
    float* cst = cstate + ((size_t)dir * Bn + b) * Hn;
    for (int d = tid; d < Hn; d += 256) {
        hs[d] = (chunk == 0) ? 0.f : hst[d];
        cs[d] = (chunk == 0) ? 0.f : cst[d];
    }
    __syncthreads();

    const float* WT  = WhhT + (size_t)(layer * 2 + dir) * Hn * G4n;
    const float* gp0 = gates + ((size_t)dir * Bn + b) * SCHn * G4n;
    const int n4 = tid << 2;            // [0,1024), float4-aligned
    const int n2 = 1024 + (tid << 1);   // [1024,1536), float2-aligned

    for (int j = 0; j < SCHn; ++j) {
        const int p = chunk * SCHn + j;
        const int s = dir ? (Sn - 1 - p) : p;
        const float* gp = gp0 + (size_t)j * G4n;

        float4 a4 = *(const float4*)(gp + n4);
        float2 a2 = *(const float2*)(gp + n2);
        const float* w4p = WT + n4;
        const float* w2p = WT + n2;

        for (int k = 0; k < Hn; k += 4) {
            const float4 hk = *(const float4*)(hs + k);
            float4 w; float2 u;
            w = *(const float4*)w4p;              u = *(const float2*)w2p;
            a4.x += hk.x * w.x; a4.y += hk.x * w.y; a4.z += hk.x * w.z; a4.w += hk.x * w.w;
            a2.x += hk.x * u.x; a2.y += hk.x * u.y;
            w = *(const float4*)(w4p + G4n);      u = *(const float2*)(w2p + G4n);
            a4.x += hk.y * w.x; a4.y += hk.y * w.y; a4.z += hk.y * w.z; a4.w += hk.y * w.w;
            a2.x += hk.y * u.x; a2.y += hk.y * u.y;
            w = *(const float4*)(w4p + 2 * G4n);  u = *(const float2*)(w2p + 2 * G4n);
            a4.x += hk.z * w.x; a4.y += hk.z * w.y; a4.z += hk.z * w.z; a4.w += hk.z * w.w;
            a2.x += hk.z * u.x; a2.y += hk.z * u.y;
            w = *(const float4*)(w4p + 3 * G4n);  u = *(const float2*)(w2p + 3 * G4n);
            a4.x += hk.w * w.x; a4.y += hk.w * w.y; a4.z += hk.w * w.z; a4.w += hk.w * w.w;
            a2.x += hk.w * u.x; a2.y += hk.w * u.y;
            w4p += 4 * G4n; w2p += 4 * G4n;
        }
        *(float4*)(gbuf + n4) = a4;
        *(float2*)(gbuf + n2) = a2;
        __syncthreads();

        // pointwise gates (PyTorch order i,f,g,o)
        for (int d = tid; d < Hn; d += 256) {
            const float ig = sigf(gbuf[d]);
            const float fg = sigf(gbuf[Hn + d]);
            const float gg = tanhf(gbuf[2 * Hn + d]);
            const float og = sigf(gbuf[3 * Hn + d]);
            const float cn = fg * cs[d] + ig * gg;
            cs[d] = cn;
            const float hn = og * tanhf(cn);
            hs[d] = hn;
            if (layer == 0) h1[((size_t)b * Sn + s) * Dn + dir * Hn + d] = hn;
        }
        __syncthreads();

        if (layer == 1 && tid < 144) {
            // fused FC partial: em_dir[t] = sum_d h[d] * fcw[t][dir*H + d]
            const int t = tid >> 4, g = tid & 15;
            const float* fw = fcw + t * Dn + dir * Hn + g * 24;
            const float* hp = hs + g * 24;
            float e = 0.f;
            #pragma unroll
            for (int q = 0; q < 24; ++q) e += hp[q] * fw[q];
            e += __shfl_down(e, 8, 16);
            e += __shfl_down(e, 4, 16);
            e += __shfl_down(e, 2, 16);
            e += __shfl_down(e, 1, 16);
            if (g == 0) emP[(((size_t)dir * Bn + b) * Sn + s) * Tn + t] = e;
        }
    }
    __syncthreads();
    for (int d = tid; d < Hn; d += 256) { hst[d] = hs[d]; cst[d] = cs[d]; }
}

// ---------------- emission combine ----------------
__global__ void em_combine(const float* __restrict__ emP, const float* __restrict__ fcb,
                           float* __restrict__ em)
{
    const int idx = blockIdx.x * 256 + threadIdx.x;
    if (idx < Bn * Sn * Tn) {
        const int t = idx % Tn;
        em[idx] = emP[idx] + emP[(size_t)Bn * Sn * Tn + idx] + fcb[t];
    }
}

// ---------------- CRF negative log-likelihood (per-batch partial) ----------------
__global__ __launch_bounds__(64) void crf_loss(
    const float* __restrict__ em, const int* __restrict__ y,
    const float* __restrict__ trans, const float* __restrict__ start_t,
    const float* __restrict__ end_t, float* __restrict__ lossp)
{
    const int b = blockIdx.x, tid = threadIdx.x;
    __shared__ float tr[Tn * Tn];
    for (int i = tid; i < Tn * Tn; i += 64) tr[i] = trans[i];
    __syncthreads();
    const int* yb = y + (size_t)b * Sn;
    const float* emb = em + (size_t)b * Sn * Tn;

    float gs = 0.f;
    for (int s2 = tid; s2 < Sn; s2 += 64) gs += emb[s2 * Tn + yb[s2]];
    for (int s2 = tid; s2 < Sn - 1; s2 += 64) gs += tr[yb[s2] * Tn + yb[s2 + 1]];
    #pragma unroll
    for (int o = 32; o > 0; o >>= 1) gs += __shfl_down(gs, o, 64);
    // lane 0 now holds gold emission+transition sum

    const int jj = (tid < Tn) ? tid : 0;
    float alpha = start_t[jj] + emb[jj];
    for (int s2 = 1; s2 < Sn; ++s2) {
        float av[Tn];
        #pragma unroll
        for (int i = 0; i < Tn; ++i) av[i] = __shfl(alpha, i, 64) + tr[i * Tn + jj];
        float m = av[0];
        #pragma unroll
        for (int i = 1; i < Tn; ++i) m = fmaxf(m, av[i]);
        float ss = 0.f;
        #pragma unroll
        for (int i = 0; i < Tn; ++i) ss += expf(av[i] - m);
        alpha = logf(ss) + m + emb[s2 * Tn + jj];
    }
    const float xv = alpha + end_t[jj];
    float m9 = -1e30f, vv[Tn];
    #pragma unroll
    for (int i = 0; i < Tn; ++i) { vv[i] = __shfl(xv, i, 64); m9 = fmaxf(m9, vv[i]); }
    float s9 = 0.f;
    #pragma unroll
    for (int i = 0; i < Tn; ++i) s9 += expf(vv[i] - m9);
    const float logZ = logf(s9) + m9;
    if (tid == 0) lossp[b] = logZ - (gs + start_t[yb[0]] + end_t[yb[Sn - 1]]);
}

__global__ __launch_bounds__(64) void loss_final(const float* __restrict__ lossp,
                                                 float* __restrict__ out)
{
    float v = lossp[threadIdx.x];
    #pragma unroll
    for (int o = 32; o > 0; o >>= 1) v += __shfl_down(v, o, 64);
    if (threadIdx.x == 0) out[0] = v * (1.f / 64.f);
}

// ---------------- Viterbi decode ----------------
__global__ __launch_bounds__(64) void viterbi_k(
    const float* __restrict__ em, const float* __restrict__ trans,
    const float* __restrict__ start_t, const float* __restrict__ end_t,
    float* __restrict__ out)
{
    const int b = blockIdx.x, tid = threadIdx.x;
    __shared__ float tr[Tn * Tn];
    __shared__ unsigned char bp[Sn - 1][16];
    __shared__ float vfin[Tn];
    for (int i = tid; i < Tn * Tn; i += 64) tr[i] = trans[i];
    __syncthreads();
    const float* emb = em + (size_t)b * Sn * Tn;
    const int jj = (tid < Tn) ? tid : 0;
    float v = start_t[jj] + emb[jj];
    for (int s2 = 1; s2 < Sn; ++s2) {
        float vv[Tn];
        #pragma unroll
        for (int i = 0; i < Tn; ++i) vv[i] = __shfl(v, i, 64);
        float best = -1e30f; int bi = 0;
        #pragma unroll
        for (int i = 0; i < Tn; ++i) {
            const float sc = vv[i] + tr[i * Tn + jj];
            if (sc > best) { best = sc; bi = i; }   // strict > == first-max (np.argmax)
        }
        if (tid < Tn) bp[s2 - 1][tid] = (unsigned char)bi;
        v = best + emb[s2 * Tn + jj];
    }
    if (tid < Tn) vfin[tid] = v + end_t[tid];
    __syncthreads();
    if (tid == 0) {
        float best = -1e30f; int cur = 0;
        for (int i = 0; i < Tn; ++i) if (vfin[i] > best) { best = vfin[i]; cur = i; }
        float* ob = out + 1 + (size_t)b * Sn;
        ob[Sn - 1] = (float)cur;
        for (int s2 = Sn - 1; s2 >= 1; --s2) { cur = bp[s2 - 1][cur]; ob[s2 - 1] = (float)cur; }
    }
}

// ---------------- launch ----------------
extern "C" void kernel_launch(void* const* d_in, const int* in_sizes, int n_in,
                              void* d_out, int out_size, void* d_ws, size_t ws_size,
                              hipStream_t stream)
{
    (void)in_sizes; (void)n_in; (void)out_size; (void)ws_size;
    const float* bert  = (const float*)d_in[0];
    const int*   y     = (const int*)d_in[1];
    const float* Wih   = (const float*)d_in[2];
    const float* Whh   = (const float*)d_in[3];
    const float* bvec  = (const float*)d_in[4];
    const float* fcw   = (const float*)d_in[5];
    const float* fcb   = (const float*)d_in[6];
    const float* trans = (const float*)d_in[7];
    const float* stt   = (const float*)d_in[8];
    const float* ent   = (const float*)d_in[9];
    float* out = (float*)d_out;
    float* ws  = (float*)d_ws;

    float* WihT  = ws + OFF_WIHT;
    float* WhhT  = ws + OFF_WHHT;
    float* gates = ws + OFF_GATES;
    float* h1    = ws + OFF_H1;
    float* emP   = ws + OFF_EMP;
    float* em    = ws + OFF_EM;
    float* hst   = ws + OFF_HST;
    float* cst   = ws + OFF_CST;
    float* lossp = ws + OFF_LP;

    transpose_w<<<dim3(4608), dim3(256), 0, stream>>>(Wih, WihT, Dn, 4 * G4n * Dn);
    transpose_w<<<dim3(2304), dim3(256), 0, stream>>>(Whh, WhhT, Hn, 4 * G4n * Hn);

    for (int l = 0; l < 2; ++l) {
        const float* A = (l == 0) ? bert : h1;
        for (int c = 0; c < NCH; ++c) {
            gemm_gates<<<dim3(12, 128), dim3(256), 0, stream>>>(A, WihT, bvec, gates, l, c);
            lstm_chunk<<<dim3(128), dim3(256), 0, stream>>>(gates, WhhT, fcw, h1, emP,
                                                            hst, cst, l, c);
        }
    }

    em_combine<<<dim3((Bn * Sn * Tn + 255) / 256), dim3(256), 0, stream>>>(emP, fcb, em);
    crf_loss<<<dim3(Bn), dim3(64), 0, stream>>>(em, y, trans, stt, ent, lossp);
    loss_final<<<dim3(1), dim3(64), 0, stream>>>(lossp, out);
    viterbi_k<<<dim3(Bn), dim3(64), 0, stream>>>(em, trans, stt, ent, out);
}